// Round 1
// baseline (252.079 us; speedup 1.0000x reference)
//
#include <hip/hip_runtime.h>
#include <hip/hip_bf16.h>

// Problem constants
#define NROWS 65536   // B*H*W*n = 2*64*64*8
#define DIM   512
#define SCALE_ 0.125f // 64^-0.5

typedef short bf16x8 __attribute__((ext_vector_type(8)));
typedef unsigned short u16x8 __attribute__((ext_vector_type(8)));
typedef float f32x4 __attribute__((ext_vector_type(4)));

__device__ __forceinline__ unsigned short f2bf(float f) {
  union { float f; unsigned u; } v; v.f = f;
  unsigned r = v.u + 0x7FFFu + ((v.u >> 16) & 1u);  // RNE
  return (unsigned short)(r >> 16);
}
__device__ __forceinline__ float bf2f(unsigned short b) {
  union { unsigned u; float f; } v; v.u = ((unsigned)b) << 16;
  return v.f;
}

// K0: weight transpose + f32->bf16.  wqkvT[j][c] = wqkv[c][j] (1536x512),
// woutT[n][c] = wout[c][n] (512x512). Grid 4096*256 = 1,048,576 = exact cover.
__global__ void prep_kernel(const float* __restrict__ wqkv,
                            const float* __restrict__ wout,
                            unsigned short* __restrict__ wqkvT,
                            unsigned short* __restrict__ woutT) {
  int idx = blockIdx.x * 256 + threadIdx.x;
  if (idx < 1536 * 512) {
    int j = idx >> 9, c = idx & 511;
    wqkvT[idx] = f2bf(wqkv[(size_t)c * 1536 + j]);
  } else {
    int k2 = idx - 1536 * 512;
    int n = k2 >> 9, c = k2 & 511;
    woutT[k2] = f2bf(wout[(size_t)c * 512 + n]);
  }
}

// K1: fused QKV projection + attention for one (M-tile of 128 rows = 16 pixels, head).
// GEMM: C[128,192] = x[r0:r0+128, :512] @ Wsel[512, 192]  (Q|K|V cols of head)
// then 8x8 masked softmax + PV per pixel; writes attn_out bf16 [65536][512].
__global__ __launch_bounds__(256, 2)
void qkv_attn_kernel(const float* __restrict__ x,
                     const float* __restrict__ mask,
                     const unsigned short* __restrict__ wqkvT,
                     unsigned short* __restrict__ attn_out) {
  // Union: phase1 A[128][72]+B[192][72] (46,080B) / phase2 C[128][208]+D[16*64 f32] (57,344B)
  __shared__ __align__(16) unsigned char smem[57344];
  unsigned short* A_lds = (unsigned short*)smem;            // [128][72] bf16
  unsigned short* B_lds = (unsigned short*)(smem + 18432);  // [192][72] bf16
  unsigned short* C_lds = (unsigned short*)smem;            // [128][208] bf16 (q|k|v)
  float*          D_lds = (float*)(smem + 53248);           // [16][8][8] dots/attn

  const int t = threadIdx.x;
  const int lane = t & 63;
  const int wave = t >> 6;
  const int wm = wave >> 1, wn = wave & 1;     // 2x2 waves, each 64x96
  const int fr = lane & 15, fq = lane >> 4;

  // XCD-bijective swizzle: 8 heads of one mtile land contiguously on one XCD
  // so the x-tile (256KB f32) is fetched from HBM once, L2-hit 7 times.
  const int per = gridDim.x >> 3;                       // 4096/8
  const int lin = (blockIdx.x & 7) * per + (blockIdx.x >> 3);
  const int mtile = lin >> 3;
  const int head  = lin & 7;
  const int r0 = mtile * 128;

  f32x4 acc[4][6];
  const f32x4 z4 = {0.f, 0.f, 0.f, 0.f};
  #pragma unroll
  for (int m = 0; m < 4; ++m)
    #pragma unroll
    for (int n = 0; n < 6; ++n) acc[m][n] = z4;

  for (int kt = 0; kt < 8; ++kt) {
    const int k0 = kt * 64;
    // stage A: x[r0+row][k0 + 0..63] f32 -> bf16. 2048 float4 chunks / 256 thr.
    #pragma unroll
    for (int i2 = 0; i2 < 8; ++i2) {
      int c = t + (i2 << 8);
      int row = c >> 4, q = c & 15;
      float4 v = *(const float4*)(x + (size_t)(r0 + row) * DIM + k0 + q * 4);
      ushort4 p;
      p.x = f2bf(v.x); p.y = f2bf(v.y); p.z = f2bf(v.z); p.w = f2bf(v.w);
      *(ushort4*)(A_lds + row * 72 + q * 4) = p;
    }
    // stage B: selected wqkvT cols (g*512 + head*64 + j) -> LDS [192][72], K-contig rows
    #pragma unroll
    for (int i2 = 0; i2 < 6; ++i2) {
      int c = t + (i2 << 8);
      int n = c >> 3, wi = c & 7;          // n: 0..191, wi: 8-bf16 chunk
      int g = n >> 6, j = n & 63;
      int jg = g * 512 + head * 64 + j;
      *(uint4*)(B_lds + n * 72 + wi * 8) =
          *(const uint4*)(wqkvT + (size_t)jg * 512 + k0 + wi * 8);
    }
    __syncthreads();
    #pragma unroll
    for (int kk = 0; kk < 2; ++kk) {
      const int krd = kk * 32 + fq * 8;
      bf16x8 a[4], b[6];
      #pragma unroll
      for (int m = 0; m < 4; ++m)
        a[m] = *(const bf16x8*)(A_lds + (wm * 64 + m * 16 + fr) * 72 + krd);
      #pragma unroll
      for (int n = 0; n < 6; ++n)
        b[n] = *(const bf16x8*)(B_lds + (wn * 96 + n * 16 + fr) * 72 + krd);
      #pragma unroll
      for (int m = 0; m < 4; ++m)
        #pragma unroll
        for (int n = 0; n < 6; ++n)
          acc[m][n] = __builtin_amdgcn_mfma_f32_16x16x32_bf16(a[m], b[n], acc[m][n], 0, 0, 0);
    }
    __syncthreads();
  }

  // spill q|k|v to LDS as bf16: C_lds[row][col], col 0..63=Q, 64..127=K, 128..191=V
  #pragma unroll
  for (int m = 0; m < 4; ++m) {
    #pragma unroll
    for (int n = 0; n < 6; ++n) {
      int col = wn * 96 + n * 16 + fr;
      #pragma unroll
      for (int j = 0; j < 4; ++j) {
        int row = wm * 64 + m * 16 + fq * 4 + j;
        C_lds[row * 208 + col] = f2bf(acc[m][n][j]);
      }
    }
  }
  __syncthreads();

  // attention: 16 pixels x 16 threads. tp: qi = tp>>1 (q row), half = tp&1.
  const int px = t >> 4, tp = t & 15;
  const int qi = tp >> 1;
  const int half = tp & 1;
  const int j0 = half * 4;
  const int rbase = px * 8;
  const int P = mtile * 16 + px;

  float dt[4];
  {
    const unsigned short* Qrow = C_lds + (rbase + qi) * 208;
    #pragma unroll
    for (int jj = 0; jj < 4; ++jj) {
      const unsigned short* Krow = C_lds + (rbase + j0 + jj) * 208 + 64;
      float s = 0.f;
      #pragma unroll
      for (int c8 = 0; c8 < 8; ++c8) {
        bf16x8 qv = *(const bf16x8*)(Qrow + c8 * 8);
        bf16x8 kv = *(const bf16x8*)(Krow + c8 * 8);
        #pragma unroll
        for (int e = 0; e < 8; ++e)
          s += bf2f((unsigned short)qv[e]) * bf2f((unsigned short)kv[e]);
      }
      dt[jj] = s;
    }
  }
  // dots * SCALE * mask -> D_lds
  const float* mrow = mask + (size_t)P * 64 + qi * 8 + j0;
  #pragma unroll
  for (int jj = 0; jj < 4; ++jj)
    D_lds[px * 64 + qi * 8 + j0 + jj] = dt[jj] * SCALE_ * mrow[jj];
  __syncthreads();

  if (tp < 8) {  // softmax over row tp of this pixel
    float* dr = D_lds + px * 64 + tp * 8;
    float mx = dr[0];
    #pragma unroll
    for (int j = 1; j < 8; ++j) mx = fmaxf(mx, dr[j]);
    float e[8], sum = 0.f;
    #pragma unroll
    for (int j = 0; j < 8; ++j) { e[j] = __expf(dr[j] - mx); sum += e[j]; }
    float inv = 1.f / sum;
    #pragma unroll
    for (int j = 0; j < 8; ++j) dr[j] = e[j] * inv;
  }
  __syncthreads();

  // PV: out[qi][d] = sum_j attn[qi][j] * V[j][d]; this thread: d in [half*32, half*32+32)
  float av[8];
  #pragma unroll
  for (int j = 0; j < 8; ++j) av[j] = D_lds[px * 64 + qi * 8 + j];
  float ov[32];
  #pragma unroll
  for (int d = 0; d < 32; ++d) ov[d] = 0.f;
  #pragma unroll
  for (int j = 0; j < 8; ++j) {
    const unsigned short* Vrow = C_lds + (rbase + j) * 208 + 128 + half * 32;
    #pragma unroll
    for (int c8 = 0; c8 < 4; ++c8) {
      bf16x8 vv = *(const bf16x8*)(Vrow + c8 * 8);
      #pragma unroll
      for (int e = 0; e < 8; ++e)
        ov[c8 * 8 + e] += av[j] * bf2f((unsigned short)vv[e]);
    }
  }
  unsigned short* orow = attn_out + (size_t)(r0 + rbase + qi) * 512 + head * 64 + half * 32;
  #pragma unroll
  for (int c8 = 0; c8 < 4; ++c8) {
    u16x8 p;
    #pragma unroll
    for (int e = 0; e < 8; ++e) p[e] = f2bf(ov[c8 * 8 + e]);
    *(u16x8*)(orow + c8 * 8) = p;
  }
}

// K2: out[65536,512] = attn[65536,512] @ wout[512,512] + bias, f32 out.
// 128x128 tile, 4 waves 2x2 each 64x64 (4x4 frags).
__global__ __launch_bounds__(256, 2)
void outproj_kernel(const unsigned short* __restrict__ attn,
                    const unsigned short* __restrict__ woutT,
                    const float* __restrict__ bias,
                    float* __restrict__ out) {
  __shared__ __align__(16) unsigned short A2[128 * 72];
  __shared__ __align__(16) unsigned short B2[128 * 72];
  const int t = threadIdx.x;
  const int lane = t & 63, wave = t >> 6;
  const int wm = wave >> 1, wn = wave & 1;
  const int fr = lane & 15, fq = lane >> 4;

  const int per = gridDim.x >> 3;      // 2048/8
  const int lin = (blockIdx.x & 7) * per + (blockIdx.x >> 3);
  const int mtile = lin >> 2, nt = lin & 3;   // nt fastest: A-panel L2 reuse
  const int r0 = mtile * 128, n0 = nt * 128;

  f32x4 acc[4][4];
  const f32x4 z4 = {0.f, 0.f, 0.f, 0.f};
  #pragma unroll
  for (int m = 0; m < 4; ++m)
    #pragma unroll
    for (int n = 0; n < 4; ++n) acc[m][n] = z4;

  for (int kt = 0; kt < 8; ++kt) {
    const int k0 = kt * 64;
    #pragma unroll
    for (int i2 = 0; i2 < 4; ++i2) {
      int c = t + (i2 << 8);
      int row = c >> 3, wi = c & 7;
      *(uint4*)(A2 + row * 72 + wi * 8) =
          *(const uint4*)(attn + (size_t)(r0 + row) * 512 + k0 + wi * 8);
      *(uint4*)(B2 + row * 72 + wi * 8) =
          *(const uint4*)(woutT + (size_t)(n0 + row) * 512 + k0 + wi * 8);
    }
    __syncthreads();
    #pragma unroll
    for (int kk = 0; kk < 2; ++kk) {
      const int krd = kk * 32 + fq * 8;
      bf16x8 a[4], b[4];
      #pragma unroll
      for (int m = 0; m < 4; ++m)
        a[m] = *(const bf16x8*)(A2 + (wm * 64 + m * 16 + fr) * 72 + krd);
      #pragma unroll
      for (int n = 0; n < 4; ++n)
        b[n] = *(const bf16x8*)(B2 + (wn * 64 + n * 16 + fr) * 72 + krd);
      #pragma unroll
      for (int m = 0; m < 4; ++m)
        #pragma unroll
        for (int n = 0; n < 4; ++n)
          acc[m][n] = __builtin_amdgcn_mfma_f32_16x16x32_bf16(a[m], b[n], acc[m][n], 0, 0, 0);
    }
    __syncthreads();
  }
  #pragma unroll
  for (int n = 0; n < 4; ++n) {
    int col = n0 + wn * 64 + n * 16 + fr;
    float bv = bias[col];
    #pragma unroll
    for (int m = 0; m < 4; ++m) {
      #pragma unroll
      for (int j = 0; j < 4; ++j) {
        int row = r0 + wm * 64 + m * 16 + fq * 4 + j;
        out[(size_t)row * 512 + col] = acc[m][n][j] + bv;
      }
    }
  }
}

extern "C" void kernel_launch(void* const* d_in, const int* in_sizes, int n_in,
                              void* d_out, int out_size, void* d_ws, size_t ws_size,
                              hipStream_t stream) {
  const float* x    = (const float*)d_in[0];  // [65536][512]
  const float* mask = (const float*)d_in[1];  // [8192][8][8]
  const float* wqkv = (const float*)d_in[2];  // [512][1536]
  const float* wout = (const float*)d_in[3];  // [512][512]
  const float* bias = (const float*)d_in[4];  // [512]
  float* out = (float*)d_out;                 // [65536][512] f32

  // ws layout: attn_out bf16 (67,108,864) | wqkvT bf16 (1,572,864) | woutT bf16 (524,288)
  unsigned char* ws = (unsigned char*)d_ws;
  unsigned short* attn  = (unsigned short*)ws;
  unsigned short* wqkvT = (unsigned short*)(ws + 67108864);
  unsigned short* woutT = (unsigned short*)(ws + 67108864 + 1572864);

  prep_kernel<<<4096, 256, 0, stream>>>(wqkv, wout, wqkvT, woutT);
  qkv_attn_kernel<<<4096, 256, 0, stream>>>(x, mask, wqkvT, attn);
  outproj_kernel<<<2048, 256, 0, stream>>>(attn, woutT, bias, out);
}

// Round 2
// 238.920 us; speedup vs baseline: 1.0551x; 1.0551x over previous
//
#include <hip/hip_runtime.h>
#include <hip/hip_bf16.h>

#define NROWS 65536   // B*H*W*n
#define DIM   512
#define SCALE_ 0.125f // 64^-0.5

typedef short bf16x8 __attribute__((ext_vector_type(8)));
typedef unsigned short u16x8 __attribute__((ext_vector_type(8)));
typedef float f32x4 __attribute__((ext_vector_type(4)));

__device__ __forceinline__ unsigned short f2bf(float f) {
  union { float f; unsigned u; } v; v.f = f;
  unsigned r = v.u + 0x7FFFu + ((v.u >> 16) & 1u);  // RNE
  return (unsigned short)(r >> 16);
}

// async global->LDS, 16B per lane. LDS dest is wave-uniform base + lane*16 (HW).
#define GLL16(gptr, lptr) \
  __builtin_amdgcn_global_load_lds((const __attribute__((address_space(1))) void*)(gptr), \
                                   (__attribute__((address_space(3))) void*)(lptr), 16, 0, 0)

// ---------------- prep: weights transpose+convert ----------------
__global__ void prep_w_kernel(const float* __restrict__ wqkv,
                              const float* __restrict__ wout,
                              unsigned short* __restrict__ wqkvT,
                              unsigned short* __restrict__ woutT) {
  int idx = blockIdx.x * 256 + threadIdx.x;
  if (idx < 1536 * 512) {
    int j = idx >> 9, c = idx & 511;
    wqkvT[idx] = f2bf(wqkv[(size_t)c * 1536 + j]);
  } else {
    int k2 = idx - 1536 * 512;
    int n = k2 >> 9, c = k2 & 511;
    woutT[k2] = f2bf(wout[(size_t)c * 512 + n]);
  }
}

// ---------------- prep: x f32 -> bf16 ----------------
__global__ void prep_x_kernel(const float* __restrict__ x,
                              unsigned short* __restrict__ xb) {
  size_t i = ((size_t)blockIdx.x * 256 + threadIdx.x) * 8;
  float4 a = *(const float4*)(x + i);
  float4 b = *(const float4*)(x + i + 4);
  u16x8 p;
  p[0] = f2bf(a.x); p[1] = f2bf(a.y); p[2] = f2bf(a.z); p[3] = f2bf(a.w);
  p[4] = f2bf(b.x); p[5] = f2bf(b.y); p[6] = f2bf(b.z); p[7] = f2bf(b.w);
  *(u16x8*)(xb + i) = p;
}

// ---------------- K1: fused QKV GEMM + attention ----------------
// grid 4096 = 512 mtiles x 8 heads. Block: 256 thr (4 waves 2x2), tile 128x192, K=512.
// AMODE 0: A staged via global_load_lds from pre-converted xb.
// AMODE 1: A reg-staged from f32 x with inline conversion (ws too small fallback).
template<int AMODE>
__global__ __launch_bounds__(256, 2)
void qkv_attn_kernel(const float* __restrict__ x,
                     const unsigned short* __restrict__ xb,
                     const float* __restrict__ mask,
                     const unsigned short* __restrict__ wqkvT,
                     unsigned short* __restrict__ attn_out) {
  // GEMM phase: dbuf, each buf = A[128][64] (16KB) + B[192][64] (24KB) = 40KB -> 80KB.
  // Epilogue union: Qs[128][64]swz @0 | Ks @16384 | VT[64][152] @32768 | Pl[8][16][40] @52224.
  __shared__ __align__(16) unsigned char smem[81920];

  const int t = threadIdx.x;
  const int lane = t & 63, wave = t >> 6;
  const int wm = wave >> 1, wn = wave & 1;
  const int fr = lane & 15, fq = lane >> 4;
  const int l8 = lane >> 3;
  const int cswz = ((lane & 7) ^ l8) * 8;   // inverse-swizzled source col (bf16 units)

  const int per = gridDim.x >> 3;
  const int lin = (blockIdx.x & 7) * per + (blockIdx.x >> 3);
  const int mtile = lin >> 3, head = lin & 7;
  const int r0 = mtile * 128;

  f32x4 acc[4][6];
  const f32x4 z4 = {0.f, 0.f, 0.f, 0.f};
  #pragma unroll
  for (int m = 0; m < 4; ++m)
    #pragma unroll
    for (int n = 0; n < 6; ++n) acc[m][n] = z4;

  auto STAGE = [&](int buf, int kt2) {
    unsigned char* base = smem + buf * 40960;
    const int k0 = kt2 * 64;
    if constexpr (AMODE == 0) {
      const unsigned short* gA = xb + (size_t)(r0 + l8) * 512 + k0 + cswz;
      #pragma unroll
      for (int i = 0; i < 4; ++i) {
        int c = wave * 4 + i;
        GLL16(gA + (size_t)c * 8 * 512, base + c * 1024);
      }
    } else {
      #pragma unroll
      for (int i2 = 0; i2 < 8; ++i2) {
        int c = t + (i2 << 8);
        int row = c >> 4, q = c & 15;
        float4 v = *(const float4*)(x + (size_t)(r0 + row) * 512 + k0 + q * 4);
        ushort4 p;
        p.x = f2bf(v.x); p.y = f2bf(v.y); p.z = f2bf(v.z); p.w = f2bf(v.w);
        unsigned byte = (unsigned)row * 128 +
                        ((((unsigned)(q >> 1)) << 4) ^ (((unsigned)(row & 7)) << 4)) +
                        (unsigned)(q & 1) * 8;
        *(ushort4*)(base + byte) = p;
      }
    }
    const unsigned short* gB = wqkvT + k0 + cswz;
    #pragma unroll
    for (int i = 0; i < 6; ++i) {
      int c = wave * 6 + i;
      int n = c * 8 + l8;
      int jg = ((n >> 6) << 9) + head * 64 + (n & 63);
      GLL16(gB + (size_t)jg * 512, base + 16384 + c * 1024);
    }
  };

  STAGE(0, 0);
  asm volatile("s_waitcnt vmcnt(0)" ::: "memory");
  __syncthreads();
  int cur = 0;

  for (int kt = 0; kt < 8; ++kt) {
    if (kt < 7) STAGE(cur ^ 1, kt + 1);
    unsigned char* Ab = smem + cur * 40960;
    unsigned char* Bb = Ab + 16384;
    const unsigned xr = ((unsigned)(fr & 7)) << 4;
    #pragma unroll
    for (int kk = 0; kk < 2; ++kk) {
      const unsigned ko = ((unsigned)(kk * 64 + fq * 16)) ^ xr;
      bf16x8 a[4], b[6];
      #pragma unroll
      for (int m = 0; m < 4; ++m)
        a[m] = *(const bf16x8*)(Ab + (unsigned)(wm * 64 + m * 16 + fr) * 128 + ko);
      #pragma unroll
      for (int n = 0; n < 6; ++n)
        b[n] = *(const bf16x8*)(Bb + (unsigned)(wn * 96 + n * 16 + fr) * 128 + ko);
      #pragma unroll
      for (int m = 0; m < 4; ++m)
        #pragma unroll
        for (int n = 0; n < 6; ++n)
          acc[m][n] = __builtin_amdgcn_mfma_f32_16x16x32_bf16(a[m], b[n], acc[m][n], 0, 0, 0);
    }
    asm volatile("s_waitcnt vmcnt(0)" ::: "memory");
    __syncthreads();
    cur ^= 1;
  }

  // ---------------- epilogue ----------------
  unsigned short* Qs = (unsigned short*)smem;             // [128][64] bf16, XOR-swz
  unsigned short* Ks = (unsigned short*)(smem + 16384);   // [128][64]
  unsigned short* VT = (unsigned short*)(smem + 32768);   // [64][152]: V^T, cols128..143 zero
  unsigned short* Pl = (unsigned short*)(smem + 52224);   // [8 pairs][16 qi][40]: P, cols16..31 zero

  {  // zero-fill VT pad cols (read as K=16..31 garbage-guard for last pair)
    int d = t >> 2, q = t & 3;
    ushort4 z; z.x = 0; z.y = 0; z.z = 0; z.w = 0;
    *(ushort4*)(VT + d * 152 + 128 + q * 4) = z;
  }
  // spill acc: Q/K scalar u16 (swizzled rows), V transposed packed ushort4
  #pragma unroll
  for (int n = 0; n < 6; ++n) {
    int col = wn * 96 + n * 16 + fr;
    #pragma unroll
    for (int m = 0; m < 4; ++m) {
      if (col < 128) {
        unsigned short* T = (col < 64) ? Qs : Ks;
        unsigned cc = (unsigned)(col & 63);
        #pragma unroll
        for (int r = 0; r < 4; ++r) {
          int row = wm * 64 + m * 16 + fq * 4 + r;
          unsigned byte = (unsigned)row * 128 + ((cc * 2) ^ (((unsigned)(row & 7)) << 4));
          *(unsigned short*)((unsigned char*)T + byte) = f2bf(acc[m][n][r]);
        }
      } else {
        int d = col - 128;
        ushort4 p;
        p.x = f2bf(acc[m][n][0]); p.y = f2bf(acc[m][n][1]);
        p.z = f2bf(acc[m][n][2]); p.w = f2bf(acc[m][n][3]);
        *(ushort4*)(VT + d * 152 + (wm * 64 + m * 16 + fq * 4)) = p;
      }
    }
  }
  __syncthreads();

  // per wave: 2 pixel-pairs; all ops below are wave-local
  #pragma unroll
  for (int pp = 0; pp < 2; ++pp) {
    const int pair = wave * 2 + pp;
    const unsigned rbyte = (unsigned)(pair * 16 + fr) * 128;
    const unsigned xrp = ((unsigned)(fr & 7)) << 4;
    // dots: S[qi][j] = Q . K^T  (16x16, cross-pixel entries masked later)
    f32x4 s = {0.f, 0.f, 0.f, 0.f};
    #pragma unroll
    for (int kk = 0; kk < 2; ++kk) {
      const unsigned ko = ((unsigned)(kk * 64 + fq * 16)) ^ xrp;
      bf16x8 qf = *(const bf16x8*)((unsigned char*)Qs + rbyte + ko);
      bf16x8 kf = *(const bf16x8*)((unsigned char*)Ks + rbyte + ko);
      s = __builtin_amdgcn_mfma_f32_16x16x32_bf16(qf, kf, s, 0, 0, 0);
    }
    // scale * mask, invalid -> -inf
    float p4[4];
    #pragma unroll
    for (int r = 0; r < 4; ++r) {
      int row = fq * 4 + r;                       // qi within pair
      bool valid = (row >> 3) == (fr >> 3);
      int Pg = mtile * 16 + pair * 2 + (row >> 3);
      float mv = mask[(size_t)Pg * 64 + (row & 7) * 8 + (fr & 7)];
      p4[r] = valid ? s[r] * SCALE_ * mv : -3.0e38f;
    }
    // softmax across j (8-lane fr-groups), fully in-register
    #pragma unroll
    for (int r = 0; r < 4; ++r) {
      float v = p4[r];
      float mx = v;
      mx = fmaxf(mx, __shfl_xor(mx, 1));
      mx = fmaxf(mx, __shfl_xor(mx, 2));
      mx = fmaxf(mx, __shfl_xor(mx, 4));
      float e = __expf(v - mx);
      float sm = e;
      sm += __shfl_xor(sm, 1);
      sm += __shfl_xor(sm, 2);
      sm += __shfl_xor(sm, 4);
      p4[r] = e / sm;
    }
    // write P (invalid entries = 0) + zero K-pad cols 16..31
    #pragma unroll
    for (int r = 0; r < 4; ++r) {
      int row = fq * 4 + r;
      bool valid = (row >> 3) == (fr >> 3);
      Pl[pair * 640 + row * 40 + fr] = valid ? f2bf(p4[r]) : (unsigned short)0;
      Pl[pair * 640 + row * 40 + 16 + fr] = 0;
    }
    // PV: D[d][qi] = VT[d][j] . P[qi][j]  (K=32: j 16..31 are zeros)
    #pragma unroll
    for (int dblk = 0; dblk < 4; ++dblk) {
      bf16x8 af = *(const bf16x8*)((unsigned char*)VT +
                    (unsigned)(dblk * 16 + fr) * 304 + (unsigned)(pair * 32 + fq * 16));
      bf16x8 bf = *(const bf16x8*)((unsigned char*)Pl +
                    (unsigned)pair * 1280 + (unsigned)fr * 80 + (unsigned)fq * 16);
      f32x4 o = {0.f, 0.f, 0.f, 0.f};
      o = __builtin_amdgcn_mfma_f32_16x16x32_bf16(af, bf, o, 0, 0, 0);
      ushort4 pk;
      pk.x = f2bf(o[0]); pk.y = f2bf(o[1]); pk.z = f2bf(o[2]); pk.w = f2bf(o[3]);
      *(ushort4*)(attn_out + (size_t)(r0 + pair * 16 + fr) * 512 +
                  head * 64 + dblk * 16 + fq * 4) = pk;
    }
  }
}

// ---------------- K2: out = attn @ woutT^T + bias (f32 out) ----------------
__global__ __launch_bounds__(256, 2)
void outproj_kernel(const unsigned short* __restrict__ attn,
                    const unsigned short* __restrict__ woutT,
                    const float* __restrict__ bias,
                    float* __restrict__ out) {
  __shared__ __align__(16) unsigned short A2[128 * 72];
  __shared__ __align__(16) unsigned short B2[128 * 72];
  const int t = threadIdx.x;
  const int lane = t & 63, wave = t >> 6;
  const int wm = wave >> 1, wn = wave & 1;
  const int fr = lane & 15, fq = lane >> 4;

  const int per = gridDim.x >> 3;
  const int lin = (blockIdx.x & 7) * per + (blockIdx.x >> 3);
  const int mtile = lin >> 2, nt = lin & 3;
  const int r0 = mtile * 128, n0 = nt * 128;

  f32x4 acc[4][4];
  const f32x4 z4 = {0.f, 0.f, 0.f, 0.f};
  #pragma unroll
  for (int m = 0; m < 4; ++m)
    #pragma unroll
    for (int n = 0; n < 4; ++n) acc[m][n] = z4;

  for (int kt = 0; kt < 8; ++kt) {
    const int k0 = kt * 64;
    #pragma unroll
    for (int i2 = 0; i2 < 4; ++i2) {
      int c = t + (i2 << 8);
      int row = c >> 3, wi = c & 7;
      *(uint4*)(A2 + row * 72 + wi * 8) =
          *(const uint4*)(attn + (size_t)(r0 + row) * 512 + k0 + wi * 8);
      *(uint4*)(B2 + row * 72 + wi * 8) =
          *(const uint4*)(woutT + (size_t)(n0 + row) * 512 + k0 + wi * 8);
    }
    __syncthreads();
    #pragma unroll
    for (int kk = 0; kk < 2; ++kk) {
      const int krd = kk * 32 + fq * 8;
      bf16x8 a[4], b[4];
      #pragma unroll
      for (int m = 0; m < 4; ++m)
        a[m] = *(const bf16x8*)(A2 + (wm * 64 + m * 16 + fr) * 72 + krd);
      #pragma unroll
      for (int n = 0; n < 4; ++n)
        b[n] = *(const bf16x8*)(B2 + (wn * 64 + n * 16 + fr) * 72 + krd);
      #pragma unroll
      for (int m = 0; m < 4; ++m)
        #pragma unroll
        for (int n = 0; n < 4; ++n)
          acc[m][n] = __builtin_amdgcn_mfma_f32_16x16x32_bf16(a[m], b[n], acc[m][n], 0, 0, 0);
    }
    __syncthreads();
  }
  #pragma unroll
  for (int n = 0; n < 4; ++n) {
    int col = n0 + wn * 64 + n * 16 + fr;
    float bv = bias[col];
    #pragma unroll
    for (int m = 0; m < 4; ++m) {
      #pragma unroll
      for (int j = 0; j < 4; ++j) {
        int row = r0 + wm * 64 + m * 16 + fq * 4 + j;
        out[(size_t)row * 512 + col] = acc[m][n][j] + bv;
      }
    }
  }
}

extern "C" void kernel_launch(void* const* d_in, const int* in_sizes, int n_in,
                              void* d_out, int out_size, void* d_ws, size_t ws_size,
                              hipStream_t stream) {
  const float* x    = (const float*)d_in[0];  // [65536][512]
  const float* mask = (const float*)d_in[1];  // [8192][8][8]
  const float* wqkv = (const float*)d_in[2];  // [512][1536]
  const float* wout = (const float*)d_in[3];  // [512][512]
  const float* bias = (const float*)d_in[4];  // [512]
  float* out = (float*)d_out;

  // ws: attn bf16 64MB | wqkvT 1.5MB | woutT 0.5MB | xb bf16 64MB
  unsigned char* ws = (unsigned char*)d_ws;
  unsigned short* attn  = (unsigned short*)ws;
  unsigned short* wqkvT = (unsigned short*)(ws + 67108864);
  unsigned short* woutT = (unsigned short*)(ws + 67108864 + 1572864);
  unsigned short* xb    = (unsigned short*)(ws + 67108864 + 1572864 + 524288);
  const size_t need_xb = 67108864ull + 1572864ull + 524288ull + 67108864ull;

  prep_w_kernel<<<4096, 256, 0, stream>>>(wqkv, wout, wqkvT, woutT);
  if (ws_size >= need_xb) {
    prep_x_kernel<<<16384, 256, 0, stream>>>(x, xb);
    qkv_attn_kernel<0><<<4096, 256, 0, stream>>>(x, xb, mask, wqkvT, attn);
  } else {
    qkv_attn_kernel<1><<<4096, 256, 0, stream>>>(x, xb, mask, wqkvT, attn);
  }
  outproj_kernel<<<2048, 256, 0, stream>>>(attn, woutT, bias, out);
}